// Round 17
// baseline (471.763 us; speedup 1.0000x reference)
//
#include <hip/hip_runtime.h>

// MsgPassingNN: 3 rounds of edge-MLP + segment_sum + node-MLP.
// N=100000 nodes (D=16), E=3200000 edges.
// fe: 32 -> 9 (relu) -> 9 (relu) -> 9 ; fx: 25 -> 9 (relu) -> 9 (relu) -> 16
//
// R19 = R18 (best verified: 466.7us) + lsb_k occupancy fix:
//   * obuf double-buffer DELETED: after the hist pass the bucket is fully
//     in LDS (buf), so the rank-scatter writes DIRECTLY to global sed
//     (reads LDS, writes global — no hazard). Scattered 4B writes stay
//     within the bucket's contiguous 16KB (L2-hot, just read from there).
//     LDS 64 -> 32KB => ~2x blocks/CU, and one 12.8MB LDS->global pass
//     is gone.
//   * everything else BYTE-IDENTICAL to R18 (frozen): edge9_k (1 thread/
//     edge, wave-scan, s_load weights), node8_k / node_last_k, bsort_k
//     (vectorized reads + bin-grouped scatter), base-prologue fused in lsb,
//     u32 sed (d_local:7|src:17), base1 stride 12 / bases stride 16,
//     fe layer-1+3 hoisted, m stride 10, node writes out in place.

constexpr int NN = 100000;
constexpr int NE = 3200000;
constexpr int NBK = (NN + 127) / 128;      // 782 buckets of 128 nodes
constexpr int SLOT = 8192;                 // sed slots per bucket (avg fill 4096)
constexpr int EPB = 4096;                  // edges per bsort block (8/thread @512)
constexpr int NBLK_SORT = (NE + EPB - 1) / EPB;   // 782
constexpr int NB_NODE = (NN + 255) / 256;  // 391

// ---------------- pass 1: bucket sort (dst>>7), LDS bin-grouped scatter ----------------
// gcursor[bin] = running count (memset to 0 before launch)

__global__ __launch_bounds__(512) void bsort_k(const int* __restrict__ src,
                                               const int* __restrict__ dst,
                                               int* __restrict__ gcursor,
                                               unsigned* __restrict__ sed)
{
    __shared__ int lhist[NBK];             // per-bin count in this block
    __shared__ int lofs[NBK];              // exclusive prefix (LDS layout)
    __shared__ int lbase[NBK];             // global base for this block's run
    __shared__ unsigned lsv[EPB];          // bin-grouped payloads (16 KB)
    __shared__ unsigned short lbin[EPB];   // bin of each LDS slot (8 KB)
    const int t = threadIdx.x;
    for (int i = t; i < NBK; i += 512) lhist[i] = 0;
    __syncthreads();

    const int blkbase = blockIdx.x * EPB;
    const int total = (NE - blkbase < EPB) ? (NE - blkbase) : EPB;
    const int start = blkbase + t * 8;     // 8 consecutive edges per thread
    unsigned pr[8], sv[8];
    if (start < NE) {                      // NE%8==0 -> all 8 valid
        const int4* ps4 = reinterpret_cast<const int4*>(src + start);
        const int4* pd4 = reinterpret_cast<const int4*>(dst + start);
        const int4 sa = ps4[0], sb = ps4[1];
        const int4 da = pd4[0], db = pd4[1];
        const int ss[8] = {sa.x, sa.y, sa.z, sa.w, sb.x, sb.y, sb.z, sb.w};
        const int dd[8] = {da.x, da.y, da.z, da.w, db.x, db.y, db.z, db.w};
        #pragma unroll
        for (int k = 0; k < 8; ++k) {
            const int bin = dd[k] >> 7;
            const int r = atomicAdd(&lhist[bin], 1);      // LDS atomic
            pr[k] = ((unsigned)bin << 13) | (unsigned)r;  // r < 4096 < 2^13
            sv[k] = ((unsigned)(dd[k] & 127) << 17) | (unsigned)ss[k];
        }
    } else {
        #pragma unroll
        for (int k = 0; k < 8; ++k) pr[k] = 0xFFFFFFFFu;
    }
    __syncthreads();

    // inclusive Hillis-Steele scan of lhist into lofs (782 wide, 2 elems/thread)
    {
        if (t < NBK) lofs[t] = lhist[t];
        const int i1 = t + 512;
        if (i1 < NBK) lofs[i1] = lhist[i1];
        __syncthreads();
        for (int off = 1; off < NBK; off <<= 1) {
            int v0 = 0, v1 = 0;
            const bool a0 = (t < NBK) && (t >= off);
            const bool a1 = (i1 < NBK) && (i1 >= off);
            if (a0) v0 = lofs[t - off];
            if (a1) v1 = lofs[i1 - off];
            __syncthreads();
            if (a0) lofs[t] += v0;
            if (a1) lofs[i1] += v1;
            __syncthreads();
        }
        // exclusive prefix + reserve the global range (1 atomic per nonempty bin)
        if (t < NBK) {
            const int c = lhist[t];
            lofs[t] -= c;
            if (c) lbase[t] = atomicAdd(&gcursor[t], c);
        }
        if (i1 < NBK) {
            const int c = lhist[i1];
            lofs[i1] -= c;
            if (c) lbase[i1] = atomicAdd(&gcursor[i1], c);
        }
        __syncthreads();
    }

    // scatter into LDS in bin-grouped order
    #pragma unroll
    for (int k = 0; k < 8; ++k) {
        if (pr[k] != 0xFFFFFFFFu) {
            const int bin = (int)(pr[k] >> 13);
            const int r = (int)(pr[k] & 0x1FFFu);
            const int pos = lofs[bin] + r;
            lsv[pos] = sv[k];
            lbin[pos] = (unsigned short)bin;
        }
    }
    __syncthreads();

    // write-out in LDS order: same-bin edges are consecutive in LDS AND in
    // the global sed region -> coalesced runs (avg 5.2 u32)
    for (int i = t; i < total; i += 512) {
        const int bin = (int)lbin[i];
        const int local = i - lofs[bin];       // == rank r of this edge
        sed[(size_t)bin * SLOT + lbase[bin] + local] = lsv[i];
    }
}

// ---- pass 2 (fused): in-bucket counting sort by d_local + base1/bases/m for
//      this bucket's 128 nodes (threads 0-127; overlaps the sort's mem phases)
//      R19: single LDS buffer; rank-scatter writes DIRECTLY to global sed.

__global__ __launch_bounds__(512) void lsb_k(unsigned* __restrict__ sed,
                                             const int* __restrict__ gcursor,
                                             const float* __restrict__ X,
                                             const float* __restrict__ feW1,
                                             const float* __restrict__ feb1,
                                             float* __restrict__ base1,
                                             float* __restrict__ bases,
                                             float* __restrict__ m)
{
    __shared__ unsigned buf[SLOT];    // 32 KB (single buffer)
    __shared__ int hist[128];
    __shared__ int cur[128];
    const int t = threadIdx.x;
    const int b = blockIdx.x;
    const int base = b * SLOT;
    int fill = gcursor[b];
    if (fill > SLOT) fill = SLOT;     // safety clamp (never hit for this input)

    // ---- fused base-prologue for this bucket's nodes (independent of sed)
    const int n = b * 128 + t;        // threads 0-127 own the bucket's nodes
    if (t < 128 && n < NN) {
        float x[16];
        const float4* p = reinterpret_cast<const float4*>(X + (size_t)n * 16);
        #pragma unroll
        for (int q = 0; q < 4; ++q) {
            float4 v = p[q];
            x[4*q] = v.x; x[4*q+1] = v.y; x[4*q+2] = v.z; x[4*q+3] = v.w;
        }
        float bd[9];
        #pragma unroll
        for (int j = 0; j < 9; ++j) bd[j] = feb1[j];
        #pragma unroll
        for (int i = 0; i < 16; ++i) {
            const float xi = x[i];
            #pragma unroll
            for (int j = 0; j < 9; ++j) bd[j] = fmaf(xi, feW1[i * 9 + j], bd[j]);
        }
        float bs[9];
        #pragma unroll
        for (int j = 0; j < 9; ++j) bs[j] = 0.f;
        #pragma unroll
        for (int i = 0; i < 16; ++i) {
            const float xi = x[i];
            #pragma unroll
            for (int j = 0; j < 9; ++j) bs[j] = fmaf(xi, feW1[(16 + i) * 9 + j], bs[j]);
        }
        float* bp = base1 + (size_t)n * 12;
        #pragma unroll
        for (int j = 0; j < 9; ++j) bp[j] = bd[j];
        float* sp = bases + (size_t)n * 16;
        #pragma unroll
        for (int j = 0; j < 9; ++j) sp[j] = bs[j];
        float* mp = m + (size_t)n * 10;
        #pragma unroll
        for (int j = 0; j < 10; ++j) mp[j] = 0.f;
    }

    // ---- in-bucket counting sort by d_local; scatter straight to global
    if (t < 128) hist[t] = 0;
    __syncthreads();
    for (int i = t; i < fill; i += 512) {
        unsigned v = sed[base + i];
        buf[i] = v;
        atomicAdd(&hist[v >> 17], 1);
    }
    __syncthreads();
    // exclusive scan of 128 bins (Hillis-Steele in LDS)
    if (t < 128) cur[t] = hist[t];
    __syncthreads();
    for (int off = 1; off < 128; off <<= 1) {
        int a = (t < 128 && t >= off) ? cur[t - off] : 0;
        __syncthreads();
        if (t < 128) cur[t] += a;
        __syncthreads();
    }
    if (t < 128) cur[t] -= hist[t];   // exclusive prefix
    __syncthreads();
    for (int i = t; i < fill; i += 512) {
        unsigned v = buf[i];
        int r = atomicAdd(&cur[v >> 17], 1);
        sed[base + r] = v;            // all of sed[bucket] already in buf
    }
}

// ---------------- edge round: 1 thread / sorted slot, wave scan of h2 ----------------
// BYTE-IDENTICAL to R10/R16/R17/R18's edge9_k (frozen local optimum).

__global__ __launch_bounds__(256) void edge9_k(
    const float* __restrict__ base1,
    const float* __restrict__ bases,
    const unsigned* __restrict__ sed,
    const int* __restrict__ gcursor,
    const float* __restrict__ feW2, const float* __restrict__ feb2,
    float* __restrict__ m)    // NN x 10: 9 h2-sums + deg
{
    const int t = threadIdx.x;
    const int b = blockIdx.x >> 5;                 // bucket (SLOT/256 = 32 blocks/bucket)
    const int idx0 = (blockIdx.x & 31) * 256;      // slot offset within bucket
    const int fill = gcursor[b];
    if (idx0 >= fill) return;                      // uniform early exit

    const int idx = idx0 + t;
    const bool valid = idx < fill;
    const int lane = t & 63;
    const int cidx = valid ? idx : fill - 1;       // clamp to a real edge
    const unsigned pk = sed[(size_t)b * SLOT + cidx];
    const int dla = (int)(pk >> 17);               // address-safe d_local
    const int s   = (int)(pk & 0x1FFFFu);
    const int dl  = valid ? dla : 128 + lane;      // sentinel: own segment

    // h1 = relu(base1[d] + base_s[s]); consecutive lanes share d -> L1 hits
    float a[9];
    {
        const float4* pb = reinterpret_cast<const float4*>(base1 + (size_t)(b * 128 + dla) * 12);
        float4 b0 = pb[0], b1 = pb[1];
        const float b8 = base1[(size_t)(b * 128 + dla) * 12 + 8];
        const float4* ps = reinterpret_cast<const float4*>(bases + (size_t)s * 16);
        float4 c0 = ps[0], c1 = ps[1];
        const float c8 = bases[(size_t)s * 16 + 8];
        a[0] = b0.x + c0.x; a[1] = b0.y + c0.y; a[2] = b0.z + c0.z; a[3] = b0.w + c0.w;
        a[4] = b1.x + c1.x; a[5] = b1.y + c1.y; a[6] = b1.z + c1.z; a[7] = b1.w + c1.w;
        a[8] = b8 + c8;
    }
    #pragma unroll
    for (int j = 0; j < 9; ++j) a[j] = fmaxf(a[j], 0.f);

    // h2 = relu(W2^T a + b2); weights via scalar loads (uniform addresses)
    float o[9];
    #pragma unroll
    for (int j = 0; j < 9; ++j) o[j] = feb2[j];
    #pragma unroll
    for (int i = 0; i < 9; ++i) {
        const float ai = a[i];
        #pragma unroll
        for (int j = 0; j < 9; ++j) o[j] = fmaf(ai, feW2[i * 9 + j], o[j]);
    }
    #pragma unroll
    for (int j = 0; j < 9; ++j) o[j] = fmaxf(o[j], 0.f);

    // segmented inclusive scan by dl over the 64-lane wave (dl sorted;
    // invalid lanes are isolated singleton segments -> garbage stays put)
    const int dprev = __shfl_up(dl, 1);
    const bool head = (lane == 0) || (dprev != dl);
    const unsigned long long hm = __ballot(head);
    const int dist = __clzll((long long)(hm << (63 - lane)));  // 0 if head
    #pragma unroll
    for (int off = 1; off < 64; off <<= 1) {
        const bool ok = (dist >= off);
        #pragma unroll
        for (int j = 0; j < 9; ++j) {
            const float ov = __shfl_up(o[j], off);
            o[j] += ok ? ov : 0.f;
        }
    }
    const bool tail = (lane == 63) || (((hm >> (lane + 1)) & 1ull) != 0ull);
    if (tail && valid) {                            // segment tail -> global m
        float* mp = m + (size_t)(b * 128 + dl) * 10;
        #pragma unroll
        for (int j = 0; j < 9; ++j) atomicAdd(mp + j, o[j]);
        atomicAdd(mp + 9, (float)(dist + 1));       // segment length = free count
    }
}

// ---------------- node round: W3/b3 + fx MLP + zero m + next bases ----------------
// BYTE-IDENTICAL to R10/R16/R17/R18's node8_k (used for rounds 0 and 1).

__global__ __launch_bounds__(256) void node8_k(
    const float* __restrict__ Xin, float* __restrict__ m,
    const float* __restrict__ fxW1, const float* __restrict__ fxb1,
    const float* __restrict__ fxW2, const float* __restrict__ fxb2,
    const float* __restrict__ fxW3, const float* __restrict__ fxb3,
    const float* __restrict__ feW1, const float* __restrict__ feb1,
    const float* __restrict__ feW3, const float* __restrict__ feb3,
    float* __restrict__ Xout, float* __restrict__ base1out,
    float* __restrict__ basesout)
{
    const int n = blockIdx.x * 256 + threadIdx.x;
    if (n >= NN) return;

    float xr[16];
    {
        const float4* p = reinterpret_cast<const float4*>(Xin + (size_t)n * 16);
        #pragma unroll
        for (int q = 0; q < 4; ++q) {
            float4 v = p[q];
            xr[4*q] = v.x; xr[4*q+1] = v.y; xr[4*q+2] = v.z; xr[4*q+3] = v.w;
        }
    }
    float S[9], deg;
    float* mp = m + (size_t)n * 10;
    #pragma unroll
    for (int j = 0; j < 9; ++j) S[j] = mp[j];
    deg = mp[9];
    #pragma unroll
    for (int j = 0; j < 10; ++j) mp[j] = 0.f;    // ready for next round

    // m = W3^T S + deg * b3   (fe layer-3, hoisted from the edge loop)
    float mm[9];
    #pragma unroll
    for (int j = 0; j < 9; ++j) mm[j] = deg * feb3[j];
    #pragma unroll
    for (int i = 0; i < 9; ++i) {
        const float si = S[i];
        #pragma unroll
        for (int j = 0; j < 9; ++j) mm[j] = fmaf(si, feW3[i * 9 + j], mm[j]);
    }

    float h1[9];
    #pragma unroll
    for (int j = 0; j < 9; ++j) h1[j] = fxb1[j];
    #pragma unroll
    for (int i = 0; i < 16; ++i) {
        const float xi = xr[i];
        #pragma unroll
        for (int j = 0; j < 9; ++j) h1[j] = fmaf(xi, fxW1[i * 9 + j], h1[j]);
    }
    #pragma unroll
    for (int i = 0; i < 9; ++i) {
        const float xi = mm[i];
        #pragma unroll
        for (int j = 0; j < 9; ++j) h1[j] = fmaf(xi, fxW1[(16 + i) * 9 + j], h1[j]);
    }
    #pragma unroll
    for (int j = 0; j < 9; ++j) h1[j] = fmaxf(h1[j], 0.f);

    float h2[9];
    #pragma unroll
    for (int j = 0; j < 9; ++j) h2[j] = fxb2[j];
    #pragma unroll
    for (int i = 0; i < 9; ++i) {
        const float xi = h1[i];
        #pragma unroll
        for (int j = 0; j < 9; ++j) h2[j] = fmaf(xi, fxW2[i * 9 + j], h2[j]);
    }
    #pragma unroll
    for (int j = 0; j < 9; ++j) h2[j] = fmaxf(h2[j], 0.f);

    float o[16];
    #pragma unroll
    for (int k = 0; k < 16; ++k) o[k] = fxb3[k];
    #pragma unroll
    for (int j = 0; j < 9; ++j) {
        const float hj = h2[j];
        #pragma unroll
        for (int k = 0; k < 16; ++k) o[k] = fmaf(hj, fxW3[j * 16 + k], o[k]);
    }

    float4* po = reinterpret_cast<float4*>(Xout + (size_t)n * 16);
    #pragma unroll
    for (int q = 0; q < 4; ++q) {
        float4 v;
        v.x = o[4*q]; v.y = o[4*q+1]; v.z = o[4*q+2]; v.w = o[4*q+3];
        po[q] = v;
    }

    // base1 / base_s for NEXT round's edge kernel
    float bb[9];
    #pragma unroll
    for (int j = 0; j < 9; ++j) bb[j] = feb1[j];
    #pragma unroll
    for (int i = 0; i < 16; ++i) {
        const float xi = o[i];
        #pragma unroll
        for (int j = 0; j < 9; ++j) bb[j] = fmaf(xi, feW1[i * 9 + j], bb[j]);
    }
    float* bp = base1out + (size_t)n * 12;
    #pragma unroll
    for (int j = 0; j < 9; ++j) bp[j] = bb[j];

    float cc[9];
    #pragma unroll
    for (int j = 0; j < 9; ++j) cc[j] = 0.f;
    #pragma unroll
    for (int i = 0; i < 16; ++i) {
        const float xi = o[i];
        #pragma unroll
        for (int j = 0; j < 9; ++j) cc[j] = fmaf(xi, feW1[(16 + i) * 9 + j], cc[j]);
    }
    float* sp = basesout + (size_t)n * 16;
    #pragma unroll
    for (int j = 0; j < 9; ++j) sp[j] = cc[j];
}

// ---------------- final node round: no base outputs, no m re-zero ----------------

__global__ __launch_bounds__(256) void node_last_k(
    const float* __restrict__ Xin, const float* __restrict__ m,
    const float* __restrict__ fxW1, const float* __restrict__ fxb1,
    const float* __restrict__ fxW2, const float* __restrict__ fxb2,
    const float* __restrict__ fxW3, const float* __restrict__ fxb3,
    const float* __restrict__ feW3, const float* __restrict__ feb3,
    float* __restrict__ Xout)
{
    const int n = blockIdx.x * 256 + threadIdx.x;
    if (n >= NN) return;

    float xr[16];
    {
        const float4* p = reinterpret_cast<const float4*>(Xin + (size_t)n * 16);
        #pragma unroll
        for (int q = 0; q < 4; ++q) {
            float4 v = p[q];
            xr[4*q] = v.x; xr[4*q+1] = v.y; xr[4*q+2] = v.z; xr[4*q+3] = v.w;
        }
    }
    float S[9], deg;
    const float* mp = m + (size_t)n * 10;
    #pragma unroll
    for (int j = 0; j < 9; ++j) S[j] = mp[j];
    deg = mp[9];

    float mm[9];
    #pragma unroll
    for (int j = 0; j < 9; ++j) mm[j] = deg * feb3[j];
    #pragma unroll
    for (int i = 0; i < 9; ++i) {
        const float si = S[i];
        #pragma unroll
        for (int j = 0; j < 9; ++j) mm[j] = fmaf(si, feW3[i * 9 + j], mm[j]);
    }

    float h1[9];
    #pragma unroll
    for (int j = 0; j < 9; ++j) h1[j] = fxb1[j];
    #pragma unroll
    for (int i = 0; i < 16; ++i) {
        const float xi = xr[i];
        #pragma unroll
        for (int j = 0; j < 9; ++j) h1[j] = fmaf(xi, fxW1[i * 9 + j], h1[j]);
    }
    #pragma unroll
    for (int i = 0; i < 9; ++i) {
        const float xi = mm[i];
        #pragma unroll
        for (int j = 0; j < 9; ++j) h1[j] = fmaf(xi, fxW1[(16 + i) * 9 + j], h1[j]);
    }
    #pragma unroll
    for (int j = 0; j < 9; ++j) h1[j] = fmaxf(h1[j], 0.f);

    float h2[9];
    #pragma unroll
    for (int j = 0; j < 9; ++j) h2[j] = fxb2[j];
    #pragma unroll
    for (int i = 0; i < 9; ++i) {
        const float xi = h1[i];
        #pragma unroll
        for (int j = 0; j < 9; ++j) h2[j] = fmaf(xi, fxW2[i * 9 + j], h2[j]);
    }
    #pragma unroll
    for (int j = 0; j < 9; ++j) h2[j] = fmaxf(h2[j], 0.f);

    float o[16];
    #pragma unroll
    for (int k = 0; k < 16; ++k) o[k] = fxb3[k];
    #pragma unroll
    for (int j = 0; j < 9; ++j) {
        const float hj = h2[j];
        #pragma unroll
        for (int k = 0; k < 16; ++k) o[k] = fmaf(hj, fxW3[j * 16 + k], o[k]);
    }

    float4* po = reinterpret_cast<float4*>(Xout + (size_t)n * 16);
    #pragma unroll
    for (int q = 0; q < 4; ++q) {
        float4 v;
        v.x = o[4*q]; v.y = o[4*q+1]; v.z = o[4*q+2]; v.w = o[4*q+3];
        po[q] = v;
    }
}

extern "C" void kernel_launch(void* const* d_in, const int* in_sizes, int n_in,
                              void* d_out, int out_size, void* d_ws, size_t ws_size,
                              hipStream_t stream)
{
    (void)in_sizes; (void)n_in; (void)out_size; (void)ws_size;
    const float* X0   = (const float*)d_in[0];
    const int*   esrc = (const int*)d_in[1];
    const int*   edst = (const int*)d_in[2];
    const float* feW1 = (const float*)d_in[3];
    const float* feb1 = (const float*)d_in[4];
    const float* feW2 = (const float*)d_in[5];
    const float* feb2 = (const float*)d_in[6];
    const float* feW3 = (const float*)d_in[7];
    const float* feb3 = (const float*)d_in[8];
    const float* fxW1 = (const float*)d_in[9];
    const float* fxb1 = (const float*)d_in[10];
    const float* fxW2 = (const float*)d_in[11];
    const float* fxb2 = (const float*)d_in[12];
    const float* fxW3 = (const float*)d_in[13];
    const float* fxb3 = (const float*)d_in[14];
    float* out = (float*)d_out;

    // workspace layout (floats unless noted). total ~41 MB.
    float* base1  = (float*)d_ws;                         // NN*12
    float* bases  = base1 + (size_t)NN * 12;              // NN*16 (64B rows)
    float* mb     = bases + (size_t)NN * 16;              // NN*10 (9 sums + deg)
    int* gcursor  = (int*)(mb + (size_t)NN * 10);         // NBK (padded to 1024)
    unsigned* sed = (unsigned*)(gcursor + 1024);          // NBK*SLOT u32 = 25.6MB

    const dim3 gS(NBLK_SORT);          // 782
    const dim3 gL(NBK);                // 782
    const dim3 gE(NBK * (SLOT / 256)); // 25024
    const dim3 gN(NB_NODE);            // 391

    // ---- sort + fused round-0 base prologue ----
    hipMemsetAsync(gcursor, 0, NBK * sizeof(int), stream);
    bsort_k<<<gS, dim3(512), 0, stream>>>(esrc, edst, gcursor, sed);
    lsb_k<<<gL, dim3(512), 0, stream>>>(sed, gcursor, X0, feW1, feb1,
                                        base1, bases, mb);

    // ---- round 0 ----
    edge9_k<<<gE, dim3(256), 0, stream>>>(base1, bases, sed, gcursor, feW2, feb2, mb);
    node8_k<<<gN, dim3(256), 0, stream>>>(X0, mb, fxW1, fxb1, fxW2, fxb2, fxW3, fxb3,
                                          feW1, feb1, feW3, feb3, out, base1, bases);
    // ---- round 1 (node updates out in place; edge never reads X) ----
    edge9_k<<<gE, dim3(256), 0, stream>>>(base1, bases, sed, gcursor, feW2, feb2, mb);
    node8_k<<<gN, dim3(256), 0, stream>>>(out, mb, fxW1, fxb1, fxW2, fxb2, fxW3, fxb3,
                                          feW1, feb1, feW3, feb3, out, base1, bases);
    // ---- round 2 (final: no base outputs, no m re-zero) ----
    edge9_k<<<gE, dim3(256), 0, stream>>>(base1, bases, sed, gcursor, feW2, feb2, mb);
    node_last_k<<<gN, dim3(256), 0, stream>>>(out, mb, fxW1, fxb1, fxW2, fxb2,
                                              fxW3, fxb3, feW3, feb3, out);
}

// Round 18
// 462.979 us; speedup vs baseline: 1.0190x; 1.0190x over previous
//
#include <hip/hip_runtime.h>

// MsgPassingNN: 3 rounds of edge-MLP + segment_sum + node-MLP.
// N=100000 nodes (D=16), E=3200000 edges.
// fe: 32 -> 9 (relu) -> 9 (relu) -> 9 ; fx: 25 -> 9 (relu) -> 9 (relu) -> 16
//
// R20 = R18 (best verified: 466.7us) restored + uint4 copy loops in lsb_k.
//   * R19's direct-to-global rank scatter REVERTED: scattered 4B global
//     writes lost more (coalescing) than the freed LDS gained (occupancy).
//     obuf double-buffer + coalesced write-back restored.
//   * NEW: lsb_k's global->LDS load and LDS->global write-back loops are
//     uint4-vectorized (8x4B -> 2x16B per thread + scalar tail). Same bytes
//     and coalescing, 4x fewer VMEM instrs over 2x12.8MB of traffic.
//     sed + b*SLOT is 32KB-aligned -> uint4 casts safe.
//   * everything else BYTE-IDENTICAL to R18 (frozen): edge9_k (1 thread/
//     edge, wave-scan, s_load weights), node8_k / node_last_k, bsort_k
//     (vectorized reads + bin-grouped scatter), base-prologue fused in lsb,
//     u32 sed (d_local:7|src:17), base1 stride 12 / bases stride 16,
//     fe layer-1+3 hoisted, m stride 10, node writes out in place.

constexpr int NN = 100000;
constexpr int NE = 3200000;
constexpr int NBK = (NN + 127) / 128;      // 782 buckets of 128 nodes
constexpr int SLOT = 8192;                 // sed slots per bucket (avg fill 4096)
constexpr int EPB = 4096;                  // edges per bsort block (8/thread @512)
constexpr int NBLK_SORT = (NE + EPB - 1) / EPB;   // 782
constexpr int NB_NODE = (NN + 255) / 256;  // 391

// ---------------- pass 1: bucket sort (dst>>7), LDS bin-grouped scatter ----------------
// gcursor[bin] = running count (memset to 0 before launch)

__global__ __launch_bounds__(512) void bsort_k(const int* __restrict__ src,
                                               const int* __restrict__ dst,
                                               int* __restrict__ gcursor,
                                               unsigned* __restrict__ sed)
{
    __shared__ int lhist[NBK];             // per-bin count in this block
    __shared__ int lofs[NBK];              // exclusive prefix (LDS layout)
    __shared__ int lbase[NBK];             // global base for this block's run
    __shared__ unsigned lsv[EPB];          // bin-grouped payloads (16 KB)
    __shared__ unsigned short lbin[EPB];   // bin of each LDS slot (8 KB)
    const int t = threadIdx.x;
    for (int i = t; i < NBK; i += 512) lhist[i] = 0;
    __syncthreads();

    const int blkbase = blockIdx.x * EPB;
    const int total = (NE - blkbase < EPB) ? (NE - blkbase) : EPB;
    const int start = blkbase + t * 8;     // 8 consecutive edges per thread
    unsigned pr[8], sv[8];
    if (start < NE) {                      // NE%8==0 -> all 8 valid
        const int4* ps4 = reinterpret_cast<const int4*>(src + start);
        const int4* pd4 = reinterpret_cast<const int4*>(dst + start);
        const int4 sa = ps4[0], sb = ps4[1];
        const int4 da = pd4[0], db = pd4[1];
        const int ss[8] = {sa.x, sa.y, sa.z, sa.w, sb.x, sb.y, sb.z, sb.w};
        const int dd[8] = {da.x, da.y, da.z, da.w, db.x, db.y, db.z, db.w};
        #pragma unroll
        for (int k = 0; k < 8; ++k) {
            const int bin = dd[k] >> 7;
            const int r = atomicAdd(&lhist[bin], 1);      // LDS atomic
            pr[k] = ((unsigned)bin << 13) | (unsigned)r;  // r < 4096 < 2^13
            sv[k] = ((unsigned)(dd[k] & 127) << 17) | (unsigned)ss[k];
        }
    } else {
        #pragma unroll
        for (int k = 0; k < 8; ++k) pr[k] = 0xFFFFFFFFu;
    }
    __syncthreads();

    // inclusive Hillis-Steele scan of lhist into lofs (782 wide, 2 elems/thread)
    {
        if (t < NBK) lofs[t] = lhist[t];
        const int i1 = t + 512;
        if (i1 < NBK) lofs[i1] = lhist[i1];
        __syncthreads();
        for (int off = 1; off < NBK; off <<= 1) {
            int v0 = 0, v1 = 0;
            const bool a0 = (t < NBK) && (t >= off);
            const bool a1 = (i1 < NBK) && (i1 >= off);
            if (a0) v0 = lofs[t - off];
            if (a1) v1 = lofs[i1 - off];
            __syncthreads();
            if (a0) lofs[t] += v0;
            if (a1) lofs[i1] += v1;
            __syncthreads();
        }
        // exclusive prefix + reserve the global range (1 atomic per nonempty bin)
        if (t < NBK) {
            const int c = lhist[t];
            lofs[t] -= c;
            if (c) lbase[t] = atomicAdd(&gcursor[t], c);
        }
        if (i1 < NBK) {
            const int c = lhist[i1];
            lofs[i1] -= c;
            if (c) lbase[i1] = atomicAdd(&gcursor[i1], c);
        }
        __syncthreads();
    }

    // scatter into LDS in bin-grouped order
    #pragma unroll
    for (int k = 0; k < 8; ++k) {
        if (pr[k] != 0xFFFFFFFFu) {
            const int bin = (int)(pr[k] >> 13);
            const int r = (int)(pr[k] & 0x1FFFu);
            const int pos = lofs[bin] + r;
            lsv[pos] = sv[k];
            lbin[pos] = (unsigned short)bin;
        }
    }
    __syncthreads();

    // write-out in LDS order: same-bin edges are consecutive in LDS AND in
    // the global sed region -> coalesced runs (avg 5.2 u32)
    for (int i = t; i < total; i += 512) {
        const int bin = (int)lbin[i];
        const int local = i - lofs[bin];       // == rank r of this edge
        sed[(size_t)bin * SLOT + lbase[bin] + local] = lsv[i];
    }
}

// ---- pass 2 (fused): in-bucket counting sort by d_local + base1/bases/m for
//      this bucket's 128 nodes (threads 0-127; overlaps the sort's mem phases)
//      R20: obuf restored (R18); uint4-vectorized copy loops.

__global__ __launch_bounds__(512) void lsb_k(unsigned* __restrict__ sed,
                                             const int* __restrict__ gcursor,
                                             const float* __restrict__ X,
                                             const float* __restrict__ feW1,
                                             const float* __restrict__ feb1,
                                             float* __restrict__ base1,
                                             float* __restrict__ bases,
                                             float* __restrict__ m)
{
    __shared__ unsigned buf[SLOT];    // 32 KB
    __shared__ unsigned obuf[SLOT];   // 32 KB
    __shared__ int hist[128];
    __shared__ int cur[128];
    const int t = threadIdx.x;
    const int b = blockIdx.x;
    const int base = b * SLOT;
    int fill = gcursor[b];
    if (fill > SLOT) fill = SLOT;     // safety clamp (never hit for this input)

    // ---- fused base-prologue for this bucket's nodes (independent of sed)
    const int n = b * 128 + t;        // threads 0-127 own the bucket's nodes
    if (t < 128 && n < NN) {
        float x[16];
        const float4* p = reinterpret_cast<const float4*>(X + (size_t)n * 16);
        #pragma unroll
        for (int q = 0; q < 4; ++q) {
            float4 v = p[q];
            x[4*q] = v.x; x[4*q+1] = v.y; x[4*q+2] = v.z; x[4*q+3] = v.w;
        }
        float bd[9];
        #pragma unroll
        for (int j = 0; j < 9; ++j) bd[j] = feb1[j];
        #pragma unroll
        for (int i = 0; i < 16; ++i) {
            const float xi = x[i];
            #pragma unroll
            for (int j = 0; j < 9; ++j) bd[j] = fmaf(xi, feW1[i * 9 + j], bd[j]);
        }
        float bs[9];
        #pragma unroll
        for (int j = 0; j < 9; ++j) bs[j] = 0.f;
        #pragma unroll
        for (int i = 0; i < 16; ++i) {
            const float xi = x[i];
            #pragma unroll
            for (int j = 0; j < 9; ++j) bs[j] = fmaf(xi, feW1[(16 + i) * 9 + j], bs[j]);
        }
        float* bp = base1 + (size_t)n * 12;
        #pragma unroll
        for (int j = 0; j < 9; ++j) bp[j] = bd[j];
        float* sp = bases + (size_t)n * 16;
        #pragma unroll
        for (int j = 0; j < 9; ++j) sp[j] = bs[j];
        float* mp = m + (size_t)n * 10;
        #pragma unroll
        for (int j = 0; j < 10; ++j) mp[j] = 0.f;
    }

    // ---- in-bucket counting sort by d_local (in place)
    if (t < 128) hist[t] = 0;
    __syncthreads();
    // load: uint4-vectorized (sed + base is 32KB-aligned)
    const int fill4 = fill >> 2;      // # of uint4 groups
    const uint4* sed4 = reinterpret_cast<const uint4*>(sed + base);
    for (int i = t; i < fill4; i += 512) {
        const uint4 v = sed4[i];
        *reinterpret_cast<uint4*>(&buf[i * 4]) = v;
        atomicAdd(&hist[v.x >> 17], 1);
        atomicAdd(&hist[v.y >> 17], 1);
        atomicAdd(&hist[v.z >> 17], 1);
        atomicAdd(&hist[v.w >> 17], 1);
    }
    for (int i = fill4 * 4 + t; i < fill; i += 512) {
        const unsigned v = sed[base + i];
        buf[i] = v;
        atomicAdd(&hist[v >> 17], 1);
    }
    __syncthreads();
    // exclusive scan of 128 bins (Hillis-Steele in LDS)
    if (t < 128) cur[t] = hist[t];
    __syncthreads();
    for (int off = 1; off < 128; off <<= 1) {
        int a = (t < 128 && t >= off) ? cur[t - off] : 0;
        __syncthreads();
        if (t < 128) cur[t] += a;
        __syncthreads();
    }
    if (t < 128) cur[t] -= hist[t];   // exclusive prefix
    __syncthreads();
    for (int i = t; i < fill; i += 512) {
        unsigned v = buf[i];
        int r = atomicAdd(&cur[v >> 17], 1);
        obuf[r] = v;
    }
    __syncthreads();
    // write-back: uint4-vectorized
    uint4* sedw4 = reinterpret_cast<uint4*>(sed + base);
    for (int i = t; i < fill4; i += 512)
        sedw4[i] = *reinterpret_cast<const uint4*>(&obuf[i * 4]);
    for (int i = fill4 * 4 + t; i < fill; i += 512)
        sed[base + i] = obuf[i];
}

// ---------------- edge round: 1 thread / sorted slot, wave scan of h2 ----------------
// BYTE-IDENTICAL to R10/R16/R17/R18's edge9_k (frozen local optimum).

__global__ __launch_bounds__(256) void edge9_k(
    const float* __restrict__ base1,
    const float* __restrict__ bases,
    const unsigned* __restrict__ sed,
    const int* __restrict__ gcursor,
    const float* __restrict__ feW2, const float* __restrict__ feb2,
    float* __restrict__ m)    // NN x 10: 9 h2-sums + deg
{
    const int t = threadIdx.x;
    const int b = blockIdx.x >> 5;                 // bucket (SLOT/256 = 32 blocks/bucket)
    const int idx0 = (blockIdx.x & 31) * 256;      // slot offset within bucket
    const int fill = gcursor[b];
    if (idx0 >= fill) return;                      // uniform early exit

    const int idx = idx0 + t;
    const bool valid = idx < fill;
    const int lane = t & 63;
    const int cidx = valid ? idx : fill - 1;       // clamp to a real edge
    const unsigned pk = sed[(size_t)b * SLOT + cidx];
    const int dla = (int)(pk >> 17);               // address-safe d_local
    const int s   = (int)(pk & 0x1FFFFu);
    const int dl  = valid ? dla : 128 + lane;      // sentinel: own segment

    // h1 = relu(base1[d] + base_s[s]); consecutive lanes share d -> L1 hits
    float a[9];
    {
        const float4* pb = reinterpret_cast<const float4*>(base1 + (size_t)(b * 128 + dla) * 12);
        float4 b0 = pb[0], b1 = pb[1];
        const float b8 = base1[(size_t)(b * 128 + dla) * 12 + 8];
        const float4* ps = reinterpret_cast<const float4*>(bases + (size_t)s * 16);
        float4 c0 = ps[0], c1 = ps[1];
        const float c8 = bases[(size_t)s * 16 + 8];
        a[0] = b0.x + c0.x; a[1] = b0.y + c0.y; a[2] = b0.z + c0.z; a[3] = b0.w + c0.w;
        a[4] = b1.x + c1.x; a[5] = b1.y + c1.y; a[6] = b1.z + c1.z; a[7] = b1.w + c1.w;
        a[8] = b8 + c8;
    }
    #pragma unroll
    for (int j = 0; j < 9; ++j) a[j] = fmaxf(a[j], 0.f);

    // h2 = relu(W2^T a + b2); weights via scalar loads (uniform addresses)
    float o[9];
    #pragma unroll
    for (int j = 0; j < 9; ++j) o[j] = feb2[j];
    #pragma unroll
    for (int i = 0; i < 9; ++i) {
        const float ai = a[i];
        #pragma unroll
        for (int j = 0; j < 9; ++j) o[j] = fmaf(ai, feW2[i * 9 + j], o[j]);
    }
    #pragma unroll
    for (int j = 0; j < 9; ++j) o[j] = fmaxf(o[j], 0.f);

    // segmented inclusive scan by dl over the 64-lane wave (dl sorted;
    // invalid lanes are isolated singleton segments -> garbage stays put)
    const int dprev = __shfl_up(dl, 1);
    const bool head = (lane == 0) || (dprev != dl);
    const unsigned long long hm = __ballot(head);
    const int dist = __clzll((long long)(hm << (63 - lane)));  // 0 if head
    #pragma unroll
    for (int off = 1; off < 64; off <<= 1) {
        const bool ok = (dist >= off);
        #pragma unroll
        for (int j = 0; j < 9; ++j) {
            const float ov = __shfl_up(o[j], off);
            o[j] += ok ? ov : 0.f;
        }
    }
    const bool tail = (lane == 63) || (((hm >> (lane + 1)) & 1ull) != 0ull);
    if (tail && valid) {                            // segment tail -> global m
        float* mp = m + (size_t)(b * 128 + dl) * 10;
        #pragma unroll
        for (int j = 0; j < 9; ++j) atomicAdd(mp + j, o[j]);
        atomicAdd(mp + 9, (float)(dist + 1));       // segment length = free count
    }
}

// ---------------- node round: W3/b3 + fx MLP + zero m + next bases ----------------
// BYTE-IDENTICAL to R10/R16/R17/R18's node8_k (used for rounds 0 and 1).

__global__ __launch_bounds__(256) void node8_k(
    const float* __restrict__ Xin, float* __restrict__ m,
    const float* __restrict__ fxW1, const float* __restrict__ fxb1,
    const float* __restrict__ fxW2, const float* __restrict__ fxb2,
    const float* __restrict__ fxW3, const float* __restrict__ fxb3,
    const float* __restrict__ feW1, const float* __restrict__ feb1,
    const float* __restrict__ feW3, const float* __restrict__ feb3,
    float* __restrict__ Xout, float* __restrict__ base1out,
    float* __restrict__ basesout)
{
    const int n = blockIdx.x * 256 + threadIdx.x;
    if (n >= NN) return;

    float xr[16];
    {
        const float4* p = reinterpret_cast<const float4*>(Xin + (size_t)n * 16);
        #pragma unroll
        for (int q = 0; q < 4; ++q) {
            float4 v = p[q];
            xr[4*q] = v.x; xr[4*q+1] = v.y; xr[4*q+2] = v.z; xr[4*q+3] = v.w;
        }
    }
    float S[9], deg;
    float* mp = m + (size_t)n * 10;
    #pragma unroll
    for (int j = 0; j < 9; ++j) S[j] = mp[j];
    deg = mp[9];
    #pragma unroll
    for (int j = 0; j < 10; ++j) mp[j] = 0.f;    // ready for next round

    // m = W3^T S + deg * b3   (fe layer-3, hoisted from the edge loop)
    float mm[9];
    #pragma unroll
    for (int j = 0; j < 9; ++j) mm[j] = deg * feb3[j];
    #pragma unroll
    for (int i = 0; i < 9; ++i) {
        const float si = S[i];
        #pragma unroll
        for (int j = 0; j < 9; ++j) mm[j] = fmaf(si, feW3[i * 9 + j], mm[j]);
    }

    float h1[9];
    #pragma unroll
    for (int j = 0; j < 9; ++j) h1[j] = fxb1[j];
    #pragma unroll
    for (int i = 0; i < 16; ++i) {
        const float xi = xr[i];
        #pragma unroll
        for (int j = 0; j < 9; ++j) h1[j] = fmaf(xi, fxW1[i * 9 + j], h1[j]);
    }
    #pragma unroll
    for (int i = 0; i < 9; ++i) {
        const float xi = mm[i];
        #pragma unroll
        for (int j = 0; j < 9; ++j) h1[j] = fmaf(xi, fxW1[(16 + i) * 9 + j], h1[j]);
    }
    #pragma unroll
    for (int j = 0; j < 9; ++j) h1[j] = fmaxf(h1[j], 0.f);

    float h2[9];
    #pragma unroll
    for (int j = 0; j < 9; ++j) h2[j] = fxb2[j];
    #pragma unroll
    for (int i = 0; i < 9; ++i) {
        const float xi = h1[i];
        #pragma unroll
        for (int j = 0; j < 9; ++j) h2[j] = fmaf(xi, fxW2[i * 9 + j], h2[j]);
    }
    #pragma unroll
    for (int j = 0; j < 9; ++j) h2[j] = fmaxf(h2[j], 0.f);

    float o[16];
    #pragma unroll
    for (int k = 0; k < 16; ++k) o[k] = fxb3[k];
    #pragma unroll
    for (int j = 0; j < 9; ++j) {
        const float hj = h2[j];
        #pragma unroll
        for (int k = 0; k < 16; ++k) o[k] = fmaf(hj, fxW3[j * 16 + k], o[k]);
    }

    float4* po = reinterpret_cast<float4*>(Xout + (size_t)n * 16);
    #pragma unroll
    for (int q = 0; q < 4; ++q) {
        float4 v;
        v.x = o[4*q]; v.y = o[4*q+1]; v.z = o[4*q+2]; v.w = o[4*q+3];
        po[q] = v;
    }

    // base1 / base_s for NEXT round's edge kernel
    float bb[9];
    #pragma unroll
    for (int j = 0; j < 9; ++j) bb[j] = feb1[j];
    #pragma unroll
    for (int i = 0; i < 16; ++i) {
        const float xi = o[i];
        #pragma unroll
        for (int j = 0; j < 9; ++j) bb[j] = fmaf(xi, feW1[i * 9 + j], bb[j]);
    }
    float* bp = base1out + (size_t)n * 12;
    #pragma unroll
    for (int j = 0; j < 9; ++j) bp[j] = bb[j];

    float cc[9];
    #pragma unroll
    for (int j = 0; j < 9; ++j) cc[j] = 0.f;
    #pragma unroll
    for (int i = 0; i < 16; ++i) {
        const float xi = o[i];
        #pragma unroll
        for (int j = 0; j < 9; ++j) cc[j] = fmaf(xi, feW1[(16 + i) * 9 + j], cc[j]);
    }
    float* sp = basesout + (size_t)n * 16;
    #pragma unroll
    for (int j = 0; j < 9; ++j) sp[j] = cc[j];
}

// ---------------- final node round: no base outputs, no m re-zero ----------------

__global__ __launch_bounds__(256) void node_last_k(
    const float* __restrict__ Xin, const float* __restrict__ m,
    const float* __restrict__ fxW1, const float* __restrict__ fxb1,
    const float* __restrict__ fxW2, const float* __restrict__ fxb2,
    const float* __restrict__ fxW3, const float* __restrict__ fxb3,
    const float* __restrict__ feW3, const float* __restrict__ feb3,
    float* __restrict__ Xout)
{
    const int n = blockIdx.x * 256 + threadIdx.x;
    if (n >= NN) return;

    float xr[16];
    {
        const float4* p = reinterpret_cast<const float4*>(Xin + (size_t)n * 16);
        #pragma unroll
        for (int q = 0; q < 4; ++q) {
            float4 v = p[q];
            xr[4*q] = v.x; xr[4*q+1] = v.y; xr[4*q+2] = v.z; xr[4*q+3] = v.w;
        }
    }
    float S[9], deg;
    const float* mp = m + (size_t)n * 10;
    #pragma unroll
    for (int j = 0; j < 9; ++j) S[j] = mp[j];
    deg = mp[9];

    float mm[9];
    #pragma unroll
    for (int j = 0; j < 9; ++j) mm[j] = deg * feb3[j];
    #pragma unroll
    for (int i = 0; i < 9; ++i) {
        const float si = S[i];
        #pragma unroll
        for (int j = 0; j < 9; ++j) mm[j] = fmaf(si, feW3[i * 9 + j], mm[j]);
    }

    float h1[9];
    #pragma unroll
    for (int j = 0; j < 9; ++j) h1[j] = fxb1[j];
    #pragma unroll
    for (int i = 0; i < 16; ++i) {
        const float xi = xr[i];
        #pragma unroll
        for (int j = 0; j < 9; ++j) h1[j] = fmaf(xi, fxW1[i * 9 + j], h1[j]);
    }
    #pragma unroll
    for (int i = 0; i < 9; ++i) {
        const float xi = mm[i];
        #pragma unroll
        for (int j = 0; j < 9; ++j) h1[j] = fmaf(xi, fxW1[(16 + i) * 9 + j], h1[j]);
    }
    #pragma unroll
    for (int j = 0; j < 9; ++j) h1[j] = fmaxf(h1[j], 0.f);

    float h2[9];
    #pragma unroll
    for (int j = 0; j < 9; ++j) h2[j] = fxb2[j];
    #pragma unroll
    for (int i = 0; i < 9; ++i) {
        const float xi = h1[i];
        #pragma unroll
        for (int j = 0; j < 9; ++j) h2[j] = fmaf(xi, fxW2[i * 9 + j], h2[j]);
    }
    #pragma unroll
    for (int j = 0; j < 9; ++j) h2[j] = fmaxf(h2[j], 0.f);

    float o[16];
    #pragma unroll
    for (int k = 0; k < 16; ++k) o[k] = fxb3[k];
    #pragma unroll
    for (int j = 0; j < 9; ++j) {
        const float hj = h2[j];
        #pragma unroll
        for (int k = 0; k < 16; ++k) o[k] = fmaf(hj, fxW3[j * 16 + k], o[k]);
    }

    float4* po = reinterpret_cast<float4*>(Xout + (size_t)n * 16);
    #pragma unroll
    for (int q = 0; q < 4; ++q) {
        float4 v;
        v.x = o[4*q]; v.y = o[4*q+1]; v.z = o[4*q+2]; v.w = o[4*q+3];
        po[q] = v;
    }
}

extern "C" void kernel_launch(void* const* d_in, const int* in_sizes, int n_in,
                              void* d_out, int out_size, void* d_ws, size_t ws_size,
                              hipStream_t stream)
{
    (void)in_sizes; (void)n_in; (void)out_size; (void)ws_size;
    const float* X0   = (const float*)d_in[0];
    const int*   esrc = (const int*)d_in[1];
    const int*   edst = (const int*)d_in[2];
    const float* feW1 = (const float*)d_in[3];
    const float* feb1 = (const float*)d_in[4];
    const float* feW2 = (const float*)d_in[5];
    const float* feb2 = (const float*)d_in[6];
    const float* feW3 = (const float*)d_in[7];
    const float* feb3 = (const float*)d_in[8];
    const float* fxW1 = (const float*)d_in[9];
    const float* fxb1 = (const float*)d_in[10];
    const float* fxW2 = (const float*)d_in[11];
    const float* fxb2 = (const float*)d_in[12];
    const float* fxW3 = (const float*)d_in[13];
    const float* fxb3 = (const float*)d_in[14];
    float* out = (float*)d_out;

    // workspace layout (floats unless noted). total ~41 MB.
    float* base1  = (float*)d_ws;                         // NN*12
    float* bases  = base1 + (size_t)NN * 12;              // NN*16 (64B rows)
    float* mb     = bases + (size_t)NN * 16;              // NN*10 (9 sums + deg)
    int* gcursor  = (int*)(mb + (size_t)NN * 10);         // NBK (padded to 1024)
    unsigned* sed = (unsigned*)(gcursor + 1024);          // NBK*SLOT u32 = 25.6MB

    const dim3 gS(NBLK_SORT);          // 782
    const dim3 gL(NBK);                // 782
    const dim3 gE(NBK * (SLOT / 256)); // 25024
    const dim3 gN(NB_NODE);            // 391

    // ---- sort + fused round-0 base prologue ----
    hipMemsetAsync(gcursor, 0, NBK * sizeof(int), stream);
    bsort_k<<<gS, dim3(512), 0, stream>>>(esrc, edst, gcursor, sed);
    lsb_k<<<gL, dim3(512), 0, stream>>>(sed, gcursor, X0, feW1, feb1,
                                        base1, bases, mb);

    // ---- round 0 ----
    edge9_k<<<gE, dim3(256), 0, stream>>>(base1, bases, sed, gcursor, feW2, feb2, mb);
    node8_k<<<gN, dim3(256), 0, stream>>>(X0, mb, fxW1, fxb1, fxW2, fxb2, fxW3, fxb3,
                                          feW1, feb1, feW3, feb3, out, base1, bases);
    // ---- round 1 (node updates out in place; edge never reads X) ----
    edge9_k<<<gE, dim3(256), 0, stream>>>(base1, bases, sed, gcursor, feW2, feb2, mb);
    node8_k<<<gN, dim3(256), 0, stream>>>(out, mb, fxW1, fxb1, fxW2, fxb2, fxW3, fxb3,
                                          feW1, feb1, feW3, feb3, out, base1, bases);
    // ---- round 2 (final: no base outputs, no m re-zero) ----
    edge9_k<<<gE, dim3(256), 0, stream>>>(base1, bases, sed, gcursor, feW2, feb2, mb);
    node_last_k<<<gN, dim3(256), 0, stream>>>(out, mb, fxW1, fxb1, fxW2, fxb2,
                                              fxW3, fxb3, feW3, feb3, out);
}